// Round 11
// baseline (615.335 us; speedup 1.0000x reference)
//
#include <hip/hip_runtime.h>

typedef float f32x4 __attribute__((ext_vector_type(4)));
typedef _Float16 f16x8 __attribute__((ext_vector_type(8)));
typedef __fp16 fp16x2 __attribute__((ext_vector_type(2)));   // cvt_pkrtz return type

#define M_TOT 16384
#define K_IN  4096
#define R_DIM 128
#define N_OUT 4096

__device__ __forceinline__ _Float16 sign_f16(float v) {
  return v > 0.f ? (_Float16)1.f : (v < 0.f ? (_Float16)-1.f : (_Float16)0.f);
}

// f32x4 pair -> f16 hi + f16 lo (pair sum accurate to ~2^-21 rel)
__device__ __forceinline__ void cvt8v(f32x4 a, f32x4 b, f16x8& h, f16x8& l) {
#pragma unroll
  for (int j = 0; j < 2; ++j) {
    fp16x2 h0 = __builtin_amdgcn_cvt_pkrtz(a[2 * j], a[2 * j + 1]);
    fp16x2 h1 = __builtin_amdgcn_cvt_pkrtz(b[2 * j], b[2 * j + 1]);
    fp16x2 l0 = __builtin_amdgcn_cvt_pkrtz(a[2 * j] - (float)h0[0], a[2 * j + 1] - (float)h0[1]);
    fp16x2 l1 = __builtin_amdgcn_cvt_pkrtz(b[2 * j] - (float)h1[0], b[2 * j + 1] - (float)h1[1]);
    h[2 * j] = (_Float16)h0[0]; h[2 * j + 1] = (_Float16)h0[1];
    h[4 + 2 * j] = (_Float16)h1[0]; h[5 + 2 * j] = (_Float16)h1[1];
    l[2 * j] = (_Float16)l0[0]; l[2 * j + 1] = (_Float16)l0[1];
    l[4 + 2 * j] = (_Float16)l1[0]; l[5 + 2 * j] = (_Float16)l1[1];
  }
}

__device__ __forceinline__ void gload16(const void* g, void* l) {
  __builtin_amdgcn_global_load_lds((const __attribute__((address_space(1))) unsigned int*)g,
                                   (__attribute__((address_space(3))) unsigned int*)l, 16, 0, 0);
}

// ---------------- prep: VsT[r][k] = sign(V[k][r]) (PLAIN layout); Us[n][r] --
__global__ __launch_bounds__(256)
void k_prep(const float* __restrict__ U, const float* __restrict__ V,
            _Float16* __restrict__ VsT, _Float16* __restrict__ Us) {
  __shared__ _Float16 tl[128 * 72];
  const int t = threadIdx.x;
  const int b = blockIdx.x;          // 0..255

  {
    size_t base = (size_t)b * 2048 + (size_t)t * 8;
    f32x4 u0 = *(const f32x4*)(U + base);
    f32x4 u1 = *(const f32x4*)(U + base + 4);
    f16x8 s;
#pragma unroll
    for (int j = 0; j < 4; ++j) { s[j] = sign_f16(u0[j]); s[j + 4] = sign_f16(u1[j]); }
    *(f16x8*)(Us + base) = s;
  }

  if (b < 64) {                      // V k-tile [64b, 64b+64)
#pragma unroll
    for (int it = 0; it < 8; ++it) {
      int idx4 = it * 256 + t;       // 0..2047
      int kl = idx4 >> 5;            // 0..63
      int r4 = (idx4 & 31) * 4;
      f32x4 v = *(const f32x4*)(V + (size_t)(b * 64 + kl) * R_DIM + r4);
#pragma unroll
      for (int j = 0; j < 4; ++j) tl[(r4 + j) * 72 + kl] = sign_f16(v[j]);
    }
    __syncthreads();
    {
      const int r = t >> 1;
      const int kh = (t & 1) * 32;
#pragma unroll
      for (int j = 0; j < 4; ++j) {
        f16x8 o = *(const f16x8*)(tl + r * 72 + kh + j * 8);
        *(f16x8*)(VsT + (size_t)r * K_IN + b * 64 + kh + j * 8) = o;
      }
    }
  }
}

// ---------------- kernel 1: Z4[q][m][r] partial GEMM, barrier-free ---------
// Block b = 16-row strip m0=b*16; wave w = K-quarter q (1024 k, 32 steps of 32).
// A direct from x (f16 hi/lo in regs), B direct from L2-resident VsT.
// 2-deep named register double-buffer; sched_barrier(0) pins prefetch issue.
#define K1LOAD(T, X0, X1, S0, S1, B0, B1, B2, B3, B4, B5, B6, B7) \
  {                                                               \
    const int koff = (T) * 32;                                    \
    X0 = *(const f32x4*)(xp + koff);                              \
    X1 = *(const f32x4*)(xp + koff + 4);                          \
    S0 = *(const f32x4*)(sp + koff);                              \
    S1 = *(const f32x4*)(sp + koff + 4);                          \
    B0 = *(const f16x8*)(bp0 + koff);                             \
    B1 = *(const f16x8*)(bp1 + koff);                             \
    B2 = *(const f16x8*)(bp2 + koff);                             \
    B3 = *(const f16x8*)(bp3 + koff);                             \
    B4 = *(const f16x8*)(bp4 + koff);                             \
    B5 = *(const f16x8*)(bp5 + koff);                             \
    B6 = *(const f16x8*)(bp6 + koff);                             \
    B7 = *(const f16x8*)(bp7 + koff);                             \
  }

#define K1COMP(X0, X1, S0, S1, B0, B1, B2, B3, B4, B5, B6, B7)          \
  {                                                                     \
    f16x8 ah, al;                                                       \
    cvt8v(X0 * S0, X1 * S1, ah, al);                                    \
    acc0 = __builtin_amdgcn_mfma_f32_16x16x32_f16(ah, B0, acc0, 0, 0, 0); \
    acc0 = __builtin_amdgcn_mfma_f32_16x16x32_f16(al, B0, acc0, 0, 0, 0); \
    acc1 = __builtin_amdgcn_mfma_f32_16x16x32_f16(ah, B1, acc1, 0, 0, 0); \
    acc1 = __builtin_amdgcn_mfma_f32_16x16x32_f16(al, B1, acc1, 0, 0, 0); \
    acc2 = __builtin_amdgcn_mfma_f32_16x16x32_f16(ah, B2, acc2, 0, 0, 0); \
    acc2 = __builtin_amdgcn_mfma_f32_16x16x32_f16(al, B2, acc2, 0, 0, 0); \
    acc3 = __builtin_amdgcn_mfma_f32_16x16x32_f16(ah, B3, acc3, 0, 0, 0); \
    acc3 = __builtin_amdgcn_mfma_f32_16x16x32_f16(al, B3, acc3, 0, 0, 0); \
    acc4 = __builtin_amdgcn_mfma_f32_16x16x32_f16(ah, B4, acc4, 0, 0, 0); \
    acc4 = __builtin_amdgcn_mfma_f32_16x16x32_f16(al, B4, acc4, 0, 0, 0); \
    acc5 = __builtin_amdgcn_mfma_f32_16x16x32_f16(ah, B5, acc5, 0, 0, 0); \
    acc5 = __builtin_amdgcn_mfma_f32_16x16x32_f16(al, B5, acc5, 0, 0, 0); \
    acc6 = __builtin_amdgcn_mfma_f32_16x16x32_f16(ah, B6, acc6, 0, 0, 0); \
    acc6 = __builtin_amdgcn_mfma_f32_16x16x32_f16(al, B6, acc6, 0, 0, 0); \
    acc7 = __builtin_amdgcn_mfma_f32_16x16x32_f16(ah, B7, acc7, 0, 0, 0); \
    acc7 = __builtin_amdgcn_mfma_f32_16x16x32_f16(al, B7, acc7, 0, 0, 0); \
  }

__global__ __launch_bounds__(256, 2)
void k1_z(const float* __restrict__ x, const float* __restrict__ s2,
          const _Float16* __restrict__ VsT, float* __restrict__ Z4) {
  const int t = threadIdx.x;
  const int lane = t & 63;
  const int q = t >> 6;                    // wave = K-quarter 0..3
  const int m0 = blockIdx.x * 16;
  const int k0 = q * 1024;
  const int kq8 = (lane >> 4) * 8;
  const int lcol = lane & 15;

  const float* xp = x + (size_t)(m0 + lcol) * K_IN + k0 + kq8;
  const float* sp = s2 + k0 + kq8;
  const _Float16* bb = VsT + (size_t)lcol * K_IN + k0 + kq8;
  const _Float16* bp0 = bb;
  const _Float16* bp1 = bb + (size_t)16 * K_IN;
  const _Float16* bp2 = bb + (size_t)32 * K_IN;
  const _Float16* bp3 = bb + (size_t)48 * K_IN;
  const _Float16* bp4 = bb + (size_t)64 * K_IN;
  const _Float16* bp5 = bb + (size_t)80 * K_IN;
  const _Float16* bp6 = bb + (size_t)96 * K_IN;
  const _Float16* bp7 = bb + (size_t)112 * K_IN;

  f32x4 acc0 = {0.f,0.f,0.f,0.f}, acc1 = acc0, acc2 = acc0, acc3 = acc0;
  f32x4 acc4 = acc0, acc5 = acc0, acc6 = acc0, acc7 = acc0;

  f32x4 xA0, xA1, sA0, sA1, xB0, xB1, sB0, sB1;
  f16x8 bA0, bA1, bA2, bA3, bA4, bA5, bA6, bA7;
  f16x8 bB0, bB1, bB2, bB3, bB4, bB5, bB6, bB7;

  K1LOAD(0, xA0, xA1, sA0, sA1, bA0, bA1, bA2, bA3, bA4, bA5, bA6, bA7);
  for (int tt = 0; tt < 16; ++tt) {
    K1LOAD((tt * 2 + 1) & 31, xB0, xB1, sB0, sB1, bB0, bB1, bB2, bB3, bB4, bB5, bB6, bB7);
    __builtin_amdgcn_sched_barrier(0);
    K1COMP(xA0, xA1, sA0, sA1, bA0, bA1, bA2, bA3, bA4, bA5, bA6, bA7);
    K1LOAD((tt * 2 + 2) & 31, xA0, xA1, sA0, sA1, bA0, bA1, bA2, bA3, bA4, bA5, bA6, bA7);
    __builtin_amdgcn_sched_barrier(0);
    K1COMP(xB0, xB1, sB0, sB1, bB0, bB1, bB2, bB3, bB4, bB5, bB6, bB7);
  }

  // epilogue: partial C store (f32), coalesced 64B per 16-lane group
  float* Zq = Z4 + (size_t)q * M_TOT * R_DIM;
  const int mrow = m0 + (lane >> 4) * 4;
#define ZST(FR, ACC)                                                   \
  _Pragma("unroll")                                                    \
  for (int j = 0; j < 4; ++j)                                          \
    Zq[(size_t)(mrow + j) * R_DIM + (FR) * 16 + lcol] = ACC[j];
  ZST(0, acc0) ZST(1, acc1) ZST(2, acc2) ZST(3, acc3)
  ZST(4, acc4) ZST(5, acc5) ZST(6, acc6) ZST(7, acc7)
#undef ZST
}

// ---------------- kernel 1r: sum 4 partials -> pre-swizzled f16 hi/lo Z ----
__global__ __launch_bounds__(256)
void k1r(const float* __restrict__ Z4,
         _Float16* __restrict__ Zswh, _Float16* __restrict__ Zswl) {
  const int idx = blockIdx.x * 256 + threadIdx.x;   // 0 .. 262143
  const int m = idx >> 4;
  const int c = (idx & 15) * 8;                     // f32 col base
  const float* p = Z4 + (size_t)m * R_DIM + c;
  const size_t QS = (size_t)M_TOT * R_DIM;
  f32x4 a0 = *(const f32x4*)(p);
  f32x4 a1 = *(const f32x4*)(p + 4);
#pragma unroll
  for (int qq = 1; qq < 4; ++qq) {
    a0 += *(const f32x4*)(p + qq * QS);
    a1 += *(const f32x4*)(p + qq * QS + 4);
  }
  f16x8 h, l;
  cvt8v(a0, a1, h, l);
  const int sw = (m & 7) << 4;
  *(f16x8*)((char*)Zswh + (size_t)m * 256 + ((c * 2) ^ sw)) = h;
  *(f16x8*)((char*)Zswl + (size_t)m * 256 + ((c * 2) ^ sw)) = l;
}

// ---------------- kernel 2 (unchanged, R9-verified) ------------------------
__global__ __launch_bounds__(256, 4)
void k2_out(const _Float16* __restrict__ Zswh, const _Float16* __restrict__ Zswl,
            const _Float16* __restrict__ Us, const float* __restrict__ s1,
            const float* __restrict__ bias, float* __restrict__ out) {
  __shared__ char smem[32768];              // Zh 16K @0, Zl 16K @16K
  const int t = threadIdx.x;
  const int lane = t & 63;
  const int wave = t >> 6;
  const int bid = blockIdx.x;
  const int nb = bid & 31;
  const int mb = bid >> 5;
  const int m0 = mb * 64, n0 = nb * 128;
  const int wm = wave & 1, wn = wave >> 1;

  f16x8 bf[4][4];
#pragma unroll
  for (int ks = 0; ks < 4; ++ks)
#pragma unroll
    for (int nf = 0; nf < 4; ++nf) {
      const int n = n0 + wn * 64 + nf * 16 + (lane & 15);
      bf[ks][nf] = *(const f16x8*)(Us + (size_t)n * R_DIM + ks * 32 + (lane >> 4) * 8);
    }

  const char* gh = (const char*)Zswh + (size_t)m0 * 256;
  const char* gl = (const char*)Zswl + (size_t)m0 * 256;
#pragma unroll
  for (int qq = 0; qq < 4; ++qq) {
    gload16(gh + wave * 1024 + qq * 4096 + lane * 16, smem + wave * 1024 + qq * 4096);
    gload16(gl + wave * 1024 + qq * 4096 + lane * 16, smem + 16384 + wave * 1024 + qq * 4096);
  }
  __syncthreads();

  f32x4 acc[2][4] = {};
  const int kq = (lane >> 4) * 16;
#pragma unroll
  for (int mf = 0; mf < 2; ++mf) {
    const int lr = wm * 32 + mf * 16 + (lane & 15);
    const int sw = (lr & 7) << 4;
#pragma unroll
    for (int ks = 0; ks < 4; ++ks) {
      const int cb = (ks * 64 + kq) ^ sw;
      f16x8 ah = *(const f16x8*)(smem + lr * 256 + cb);
      f16x8 al = *(const f16x8*)(smem + 16384 + lr * 256 + cb);
#pragma unroll
      for (int nf = 0; nf < 4; ++nf) {
        acc[mf][nf] = __builtin_amdgcn_mfma_f32_16x16x32_f16(ah, bf[ks][nf], acc[mf][nf], 0, 0, 0);
        acc[mf][nf] = __builtin_amdgcn_mfma_f32_16x16x32_f16(al, bf[ks][nf], acc[mf][nf], 0, 0, 0);
      }
    }
  }

#pragma unroll
  for (int nf = 0; nf < 4; ++nf) {
    const int col = n0 + wn * 64 + nf * 16 + (lane & 15);
    const float sv = s1[col];
    const float bv = bias[col];
#pragma unroll
    for (int mf = 0; mf < 2; ++mf) {
      const int row = m0 + wm * 32 + mf * 16 + (lane >> 4) * 4;
#pragma unroll
      for (int j = 0; j < 4; ++j)
        out[(size_t)(row + j) * N_OUT + col] = acc[mf][nf][j] * sv + bv;
    }
  }
}

extern "C" void kernel_launch(void* const* d_in, const int* in_sizes, int n_in,
                              void* d_out, int out_size, void* d_ws, size_t ws_size,
                              hipStream_t stream) {
  const float* x    = (const float*)d_in[0];
  const float* U    = (const float*)d_in[1];
  const float* V    = (const float*)d_in[2];
  const float* s1   = (const float*)d_in[3];
  const float* s2   = (const float*)d_in[4];
  const float* bias = (const float*)d_in[5];
  float* out = (float*)d_out;

  // ws: VsT 1MB | Us 1MB | Zswh 4MB | Zswl 4MB | Z4 32MB
  char* w = (char*)d_ws;
  _Float16* VsT  = (_Float16*)(w);
  _Float16* Us   = (_Float16*)(w + (1 << 20));
  _Float16* Zswh = (_Float16*)(w + (2 << 20));
  _Float16* Zswl = (_Float16*)(w + (6 << 20));
  float*    Z4   = (float*)(w + (10 << 20));

  k_prep<<<dim3(256), dim3(256), 0, stream>>>(U, V, VsT, Us);
  k1_z<<<dim3(1024), dim3(256), 0, stream>>>(x, s2, VsT, Z4);
  k1r<<<dim3(1024), dim3(256), 0, stream>>>(Z4, Zswh, Zswl);
  k2_out<<<dim3(8192), dim3(256), 0, stream>>>(Zswh, Zswl, Us, s1, bias, out);
}